// Round 3
// baseline (1605.488 us; speedup 1.0000x reference)
//
#include <hip/hip_runtime.h>

#define SEQ 1024
#define NHEAD 16
#define DHEAD 64

// ---------------- RoPE cos/sin table: rope[pos*64 + i]=cos, [pos*64+32+i]=sin ----------------
__global__ void rope_table_kernel(float* __restrict__ rope){
  int idx = blockIdx.x * 256 + threadIdx.x;
  if (idx >= 2048 * 32) return;
  int pos = idx >> 5, i = idx & 31;
  double freq = pow(10000.0, -(double)i / 32.0);
  double a = (double)pos * freq;
  rope[pos * 64 + i]      = (float)cos(a);
  rope[pos * 64 + 32 + i] = (float)sin(a);
}

// ------- out[M=2048,1024] = A[2048,1024] @ W[1024,1024]^T + bias; mode1: RoPE epilogue -------
__global__ __launch_bounds__(256) void gemm_kernel(
    const float* __restrict__ A, const float* __restrict__ W,
    const float* __restrict__ bias, float* __restrict__ out,
    const float* __restrict__ rope, const int* __restrict__ pos_ids, int mode)
{
  __shared__ float As[64][68];
  __shared__ float Ws[64][68];
  int t = threadIdx.x;
  int tx = t & 15, ty = t >> 4;
  int row0 = blockIdx.y << 6, col0 = blockIdx.x << 6;
  float acc[4][4];
  #pragma unroll
  for (int a = 0; a < 4; a++)
    #pragma unroll
    for (int c = 0; c < 4; c++) acc[a][c] = 0.f;
  float bvv[4];
  #pragma unroll
  for (int j = 0; j < 4; j++) bvv[j] = bias[col0 + tx + 16*j];

  for (int kt = 0; kt < 1024; kt += 64){
    #pragma unroll
    for (int jj = 0; jj < 4; jj++){
      int flat = t + jj*256;
      int r = flat >> 4, c4 = (flat & 15) << 2;
      *(float4*)&As[r][c4] = *(const float4*)(A + (size_t)(row0 + r)*1024 + kt + c4);
      *(float4*)&Ws[r][c4] = *(const float4*)(W + (size_t)(col0 + r)*1024 + kt + c4);
    }
    __syncthreads();
    #pragma unroll
    for (int i4 = 0; i4 < 16; i4++){
      float4 a4[4], b4[4];
      #pragma unroll
      for (int j = 0; j < 4; j++){
        a4[j] = *(float4*)&As[ty + 16*j][i4 << 2];
        b4[j] = *(float4*)&Ws[tx + 16*j][i4 << 2];
      }
      #pragma unroll
      for (int jr = 0; jr < 4; jr++)
        #pragma unroll
        for (int jc = 0; jc < 4; jc++)
          acc[jr][jc] += a4[jr].x*b4[jc].x + a4[jr].y*b4[jc].y + a4[jr].z*b4[jc].z + a4[jr].w*b4[jc].w;
    }
    __syncthreads();
  }
  // stage C (with bias) into LDS for RoPE pairing + coalesced store
  #pragma unroll
  for (int jr = 0; jr < 4; jr++)
    #pragma unroll
    for (int jc = 0; jc < 4; jc++)
      As[ty + 16*jr][tx + 16*jc] = acc[jr][jc] + bvv[jc];
  __syncthreads();
  #pragma unroll
  for (int jj = 0; jj < 16; jj++){
    int flat = t + jj*256;
    int r = flat >> 6, c = flat & 63;
    int grow = row0 + r;
    float x = As[r][c];
    if (mode){
      float p = As[r][c ^ 32];
      int pos = pos_ids[grow];
      pos = pos < 0 ? 0 : (pos > 2047 ? 2047 : pos);
      int i = c & 31;
      float cs = rope[pos*64 + i];
      float sn = rope[pos*64 + 32 + i];
      x = (c < 32) ? (x*cs - p*sn) : (x*cs + p*sn);
    }
    out[(size_t)grow*1024 + col0 + c] = x;
  }
}

// ---------------- attention: one block per (b,q) row, all 16 heads ----------------
__global__ __launch_bounds__(512) void attn_kernel(
    const float* __restrict__ qw, const float* __restrict__ kw,
    const float* __restrict__ vw,
    const float* __restrict__ relk, const float* __restrict__ relv,
    const float* __restrict__ wpre_g, const float* __restrict__ wpost_g,
    const int* __restrict__ qpos_g, const int* __restrict__ kpos_g,
    float* __restrict__ ctx)
{
  __shared__ float relv_s[129][68];   // rel_v rows 128..256 (causal => only these used)
  __shared__ float qrel_s[16][132];   // qrel[n][r] = q_n . rel_k[128+r]
  __shared__ float qrow_s[16][68];
  __shared__ float ub1[16][36];
  __shared__ float ub2[16][36];
  __shared__ float red[32][16];
  __shared__ float wpre_s[16][17];
  __shared__ float wpost_s[16][17];
  __shared__ int   rels[32];
  __shared__ float mrow[16];
  __shared__ float invl[16];

  int t = threadIdx.x;
  int bid = blockIdx.x;
  int b = bid & 1;
  int q = (SEQ - 1) - (bid >> 1);   // longest rows dispatched first
  size_t browq = (size_t)(b*SEQ + q);

  for (int f = t; f < 1024; f += 512)
    qrow_s[f >> 6][f & 63] = qw[browq*1024 + f];
  if (t < 256) wpre_s[t >> 4][t & 15] = wpre_g[t];
  else { int u = t - 256; wpost_s[u >> 4][u & 15] = wpost_g[u]; }
  for (int e = t; e < 129*64; e += 512){
    int r = e >> 6, d = e & 63;
    relv_s[r][d] = relv[(size_t)(128 + r)*64 + d];
  }
  __syncthreads();

  int m16 = t & 15, kj = t >> 4;  // kj in 0..31
  for (int r = kj; r < 129; r += 32){
    const float* rk = relk + (size_t)(128 + r)*64;
    float s = 0.f;
    #pragma unroll
    for (int d4 = 0; d4 < 64; d4 += 4){
      float4 pv = *(const float4*)(rk + d4);
      float4 qv = *(const float4*)&qrow_s[m16][d4];
      s += qv.x*pv.x + qv.y*pv.y + qv.z*pv.z + qv.w*pv.w;
    }
    qrel_s[m16][r] = s;
  }
  int qp = qpos_g[b*SEQ + q];
  __syncthreads();

  int nk = q + 1;
  int nct = (nk + 31) >> 5;
  float sreg[32];
  #pragma unroll
  for (int i = 0; i < 32; i++) sreg[i] = -1e30f;

  // scores: s = (q.k + q.rel_k)/8, then pre-softmax head mix (w_pre)
  for (int ci = 0; ci < nct; ci++){
    int k = (ci << 5) + kj;
    float uval = 0.f;
    if (k < nk){
      const float* kv = kw + ((size_t)(b*SEQ + k))*1024 + m16*64;
      float s = 0.f;
      #pragma unroll
      for (int d4 = 0; d4 < 64; d4 += 4){
        float4 pv = *(const float4*)(kv + d4);
        float4 qv = *(const float4*)&qrow_s[m16][d4];
        s += qv.x*pv.x + qv.y*pv.y + qv.z*pv.z + qv.w*pv.w;
      }
      int kp = kpos_g[b*SEQ + k];
      int rd = qp - kp; rd = rd > 128 ? 128 : (rd < 0 ? 0 : rd);
      uval = (s + qrel_s[m16][rd]) * 0.125f;
    }
    ub1[m16][kj] = uval;
    __syncthreads();
    if (k < nk){
      float acc2 = 0.f;
      #pragma unroll
      for (int n = 0; n < 16; n++) acc2 += ub1[n][kj] * wpre_s[n][m16];
      sreg[ci] = acc2;   // thread (m16,kj) owns score[m16][32*ci+kj]
    }
    __syncthreads();
  }

  // exact softmax per head row (masked lanes hold -1e30 -> exp == 0)
  float loc = -1e30f;
  for (int i = 0; i < nct; i++) loc = fmaxf(loc, sreg[i]);
  red[kj][m16] = loc;
  __syncthreads();
  if (t < 16){
    float v = -1e30f;
    #pragma unroll
    for (int s2 = 0; s2 < 32; s2++) v = fmaxf(v, red[s2][t]);
    mrow[t] = v;
  }
  __syncthreads();
  float mm = mrow[m16];
  float ls = 0.f;
  for (int i = 0; i < nct; i++){
    float arg = sreg[i] - mm;
    arg = fmaxf(arg, -80.f);          // masked lanes -> exp(-80) ~ 1.8e-35, negligible
    float p = __expf(arg);
    sreg[i] = p;
    ls += p;
  }
  red[kj][m16] = ls;
  __syncthreads();
  if (t < 16){
    float v = 0.f;
    #pragma unroll
    for (int s2 = 0; s2 < 32; s2++) v += red[s2][t];
    invl[t] = 1.f / v;
  }
  __syncthreads();
  // fold 1/l into w_post
  if (t < 256){ int m = t >> 4, n = t & 15; wpost_s[m][n] *= invl[m]; }
  __syncthreads();

  // post-mix + PV with fused rel_v
  int nn = t >> 5, d0 = (t & 31) << 1;
  float a0 = 0.f, a1 = 0.f;
  for (int ci = 0; ci < nct; ci++){
    int kb = ci << 5;
    ub1[m16][kj] = sreg[ci];
    if (t < 32){
      int k = kb + t, rd = 0;
      if (k < nk){ int kp = kpos_g[b*SEQ + k]; rd = qp - kp; rd = rd > 128 ? 128 : (rd < 0 ? 0 : rd); }
      rels[t] = rd;
    }
    __syncthreads();
    {
      int k = kb + kj;
      float acc2 = 0.f;
      if (k < nk){
        #pragma unroll
        for (int m = 0; m < 16; m++) acc2 += ub1[m][kj] * wpost_s[m][m16];
      }
      ub2[m16][kj] = acc2;
    }
    __syncthreads();
    int lim = nk - kb; lim = lim > 32 ? 32 : lim;
    const float* vb = vw + ((size_t)(b*SEQ + kb))*1024 + nn*64 + d0;
    for (int j = 0; j < lim; j++){
      float w = ub2[nn][j];
      float2 pv = *(const float2*)(vb + (size_t)j*1024);
      int rd = rels[j];
      a0 += w * (pv.x + relv_s[rd][d0]);
      a1 += w * (pv.y + relv_s[rd][d0 + 1]);
    }
    __syncthreads();
  }
  float2 res; res.x = a0; res.y = a1;
  *(float2*)(ctx + browq*1024 + nn*64 + d0) = res;
}

extern "C" void kernel_launch(void* const* d_in, const int* in_sizes, int n_in,
                              void* d_out, int out_size, void* d_ws, size_t ws_size,
                              hipStream_t stream)
{
  // Robust input indexing: q_pos_ids is the FIRST input with 2048 elements
  // (query/key/value/attn_mask are >=2M, weights 1M, biases 1024, rel tables
  // 16448, w_pre/w_post 256). Anchors the layout whether or not the bool
  // attn_mask occupies a slot.
  int ip = -1;
  for (int i = 0; i < n_in; i++){
    if (in_sizes[i] == 2048){ ip = i; break; }
  }
  if (ip < 0) ip = 4;  // fallback: reference dict order with mask at 3

  const float* query = (const float*)d_in[0];
  const float* key   = (const float*)d_in[1];
  const float* value = (const float*)d_in[2];
  const int* qpos = (const int*)d_in[ip];
  const int* kpos = (const int*)d_in[ip + 1];
  const float* Wq    = (const float*)d_in[ip + 2];
  const float* bq    = (const float*)d_in[ip + 3];
  const float* Wk    = (const float*)d_in[ip + 4];
  const float* bk    = (const float*)d_in[ip + 5];
  const float* Wv    = (const float*)d_in[ip + 6];
  const float* b_v   = (const float*)d_in[ip + 7];
  const float* Wo    = (const float*)d_in[ip + 8];
  const float* bo    = (const float*)d_in[ip + 9];
  const float* relk  = (const float*)d_in[ip + 10];
  const float* relv  = (const float*)d_in[ip + 11];
  const float* wpre  = (const float*)d_in[ip + 12];
  const float* wpost = (const float*)d_in[ip + 13];

  char* ws = (char*)d_ws;
  float* rope = (float*)ws;                                   // 512 KB
  float* q_ws = (float*)(ws + 524288);                        // 8 MB each (fp32)
  float* k_ws = (float*)(ws + 524288 + 8388608);
  float* v_ws = (float*)(ws + 524288 + 2*8388608);
  float* ctx  = (float*)(ws + 524288 + 3*8388608);

  hipLaunchKernelGGL(rope_table_kernel, dim3(256), dim3(256), 0, stream, rope);
  dim3 gg(16, 32);
  hipLaunchKernelGGL(gemm_kernel, gg, dim3(256), 0, stream, query, Wq, bq, q_ws, rope, qpos, 1);
  hipLaunchKernelGGL(gemm_kernel, gg, dim3(256), 0, stream, key,   Wk, bk, k_ws, rope, kpos, 1);
  hipLaunchKernelGGL(gemm_kernel, gg, dim3(256), 0, stream, value, Wv, b_v, v_ws, rope, qpos, 0);
  hipLaunchKernelGGL(attn_kernel, dim3(2048), dim3(512), 0, stream,
                     q_ws, k_ws, v_ws, relk, relv, wpre, wpost, qpos, kpos, ctx);
  hipLaunchKernelGGL(gemm_kernel, gg, dim3(256), 0, stream, ctx, Wo, bo,
                     (float*)d_out, rope, qpos, 0);
}